// Round 2
// baseline (2389.748 us; speedup 1.0000x reference)
//
#include <hip/hip_runtime.h>
#include <hip/hip_bf16.h>

#define BB 256      // batches
#define P 64        // cluster dim
#define MM 4096     // samples per row
#define MC 128      // chunk columns for cov staging
#define MT 256      // tile columns for apply

// ---------------- Kernel A: partial sums for covariance ----------------
// grid (BB, nsplit), block 256 (4 waves sharing one LDS chunk buffer).
// Each wave consumes a 32-column slice of the staged 64x128 chunk with
// 8x8 register blocking (conflict-free b128 broadcasts: 8 distinct rows,
// row stride 132 -> start banks 4*br+const cover all 32 banks once).
__global__ __launch_bounds__(256, 4)
void covpart_kernel(const float* __restrict__ x, float* __restrict__ s2p,
                    float* __restrict__ s1p, int nsplit)
{
    __shared__ __align__(16) float Xs[P][MC + 4];   // 64 x 132 = 33.8 KB
    __shared__ float s1red[4][P];
    const int b = blockIdx.x, sp = blockIdx.y;
    const int t = threadIdx.x;
    const int w = t >> 6, l = t & 63;
    const int mlen = MM / nsplit;
    const float* xb = x + (size_t)b * (P * MM) + (size_t)sp * mlen;
    const int br = l >> 3, bc = l & 7;
    const int mw = w * 32;                          // this wave's column slice

    float acc[8][8];
    #pragma unroll
    for (int i = 0; i < 8; ++i)
        #pragma unroll
        for (int k = 0; k < 8; ++k) acc[i][k] = 0.f;
    float s1[8] = {0.f,0.f,0.f,0.f,0.f,0.f,0.f,0.f};

    const int nch = mlen / MC;
    for (int ch = 0; ch < nch; ++ch) {
        const int m0 = ch * MC;
        __syncthreads();
        #pragma unroll
        for (int j = 0; j < 8; ++j) {               // 2048 float4s, 256 thr
            int f4 = t + 256 * j;
            int r = f4 >> 5, c = (f4 & 31) << 2;
            *reinterpret_cast<float4*>(&Xs[r][c]) =
                *reinterpret_cast<const float4*>(xb + (size_t)r * MM + m0 + c);
        }
        __syncthreads();
        #pragma unroll
        for (int mg = 0; mg < 32; mg += 4) {
            float a[8][4];
            #pragma unroll
            for (int i = 0; i < 8; ++i)
                *reinterpret_cast<float4*>(a[i]) =
                    *reinterpret_cast<const float4*>(&Xs[br + 8 * i][mw + mg]);
            #pragma unroll
            for (int k = 0; k < 8; ++k) {
                float bv[4];
                *reinterpret_cast<float4*>(bv) =
                    *reinterpret_cast<const float4*>(&Xs[bc + 8 * k][mw + mg]);
                #pragma unroll
                for (int i = 0; i < 8; ++i)
                    acc[i][k] += a[i][0] * bv[0] + a[i][1] * bv[1]
                               + a[i][2] * bv[2] + a[i][3] * bv[3];
            }
            if (bc == 0) {
                #pragma unroll
                for (int i = 0; i < 8; ++i)
                    s1[i] += a[i][0] + a[i][1] + a[i][2] + a[i][3];
            }
        }
    }

    // cross-wave reduction: reuse Xs as red[64][68] (17.4 KB <= 33.8 KB)
    float (*red)[68] = reinterpret_cast<float (*)[68]>(&Xs[0][0]);
    #pragma unroll
    for (int wv = 0; wv < 4; ++wv) {
        __syncthreads();
        if (w == wv) {
            #pragma unroll
            for (int i = 0; i < 8; ++i)
                #pragma unroll
                for (int k = 0; k < 8; ++k) {
                    if (wv == 0) red[br + 8 * i][bc + 8 * k]  = acc[i][k];
                    else         red[br + 8 * i][bc + 8 * k] += acc[i][k];
                }
            if (bc == 0) {
                #pragma unroll
                for (int i = 0; i < 8; ++i) s1red[wv][br + 8 * i] = s1[i];
            }
        }
    }
    __syncthreads();
    float* s2b = s2p + ((size_t)sp * BB + b) * (P * P);
    #pragma unroll
    for (int j = 0; j < 16; ++j) {
        int f = t + 256 * j;
        s2b[f] = red[f >> 6][f & 63];
    }
    if (t < P) {
        s1p[((size_t)sp * BB + b) * P + t] =
            s1red[0][t] + s1red[1][t] + s1red[2][t] + s1red[3][t];
    }
}

// ---------------- Kernel B: shrinkage + Newton-Schulz inverse sqrt ----------------
typedef float (*Mat68)[68];

// D = alpha * (A^T * B) + beta * I ; A symmetric => A^T*B == A*B.
// Column reads of A become contiguous row reads via symmetry (float4).
__device__ inline void mm64f(Mat68 D, Mat68 A, Mat68 Bm, int t, float alpha, float beta)
{
    __syncthreads();
    const int r0 = (t >> 4) * 4, c0 = (t & 15) * 4;
    float acc[4][4];
    #pragma unroll
    for (int i = 0; i < 4; ++i)
        #pragma unroll
        for (int j = 0; j < 4; ++j) acc[i][j] = 0.f;
    #pragma unroll 4
    for (int k = 0; k < P; ++k) {
        float av[4], bv[4];
        *reinterpret_cast<float4*>(av) = *reinterpret_cast<const float4*>(&A[k][r0]);
        *reinterpret_cast<float4*>(bv) = *reinterpret_cast<const float4*>(&Bm[k][c0]);
        #pragma unroll
        for (int i = 0; i < 4; ++i)
            #pragma unroll
            for (int j = 0; j < 4; ++j) acc[i][j] += av[i] * bv[j];
    }
    __syncthreads();
    #pragma unroll
    for (int i = 0; i < 4; ++i)
        #pragma unroll
        for (int j = 0; j < 4; ++j)
            D[r0 + i][c0 + j] = alpha * acc[i][j] + ((r0 + i) == (c0 + j) ? beta : 0.f);
}

__global__ __launch_bounds__(256)
void whiten_kernel(const float* __restrict__ s2p, const float* __restrict__ s1p,
                   float* __restrict__ shat, float* __restrict__ tvec, int nsplit)
{
    __shared__ __align__(16) float B0[P][68], B1[P][68], B2[P][68], B3[P][68], B4[P][68];
    __shared__ float mus[P];
    __shared__ float red[2][4];
    const int b = blockIdx.x, t = threadIdx.x;

    if (t < P) {
        float s = 0.f;
        for (int sp = 0; sp < nsplit; ++sp) s += s1p[((size_t)sp * BB + b) * P + t];
        mus[t] = s * (1.0f / MM);
    }
    __syncthreads();

    // assemble C = S2/M - mu mu^T into B0; accumulate trace and tr(C^2)
    float tr_part = 0.f, s2_part = 0.f;
    #pragma unroll
    for (int j = 0; j < 16; ++j) {
        int f = t + 256 * j;
        int i = f >> 6, jc = f & 63;
        float sum = 0.f;
        for (int sp = 0; sp < nsplit; ++sp)
            sum += s2p[((size_t)sp * BB + b) * (P * P) + f];
        float v = sum * (1.0f / MM) - mus[i] * mus[jc];
        B0[i][jc] = v;
        s2_part += v * v;
        if (i == jc) tr_part += v;
    }
    #pragma unroll
    for (int off = 32; off > 0; off >>= 1) {
        tr_part += __shfl_down(tr_part, off);
        s2_part += __shfl_down(s2_part, off);
    }
    if ((t & 63) == 0) { red[0][t >> 6] = tr_part; red[1][t >> 6] = s2_part; }
    __syncthreads();
    const float trace = red[0][0] + red[0][1] + red[0][2] + red[0][3];
    const float sum2  = red[1][0] + red[1][1] + red[1][2] + red[1][3];

    const float nf = (float)MM;
    const float num = (nf - 2.0f) / nf * sum2 + trace * trace;
    const float den = (nf + 2.0f) * (sum2 - trace * trace / (float)P);
    const float rho = (den > 0.f) ? fminf(num / den, 1.0f) : 1.0f;
    const float lam = trace * (1.0f / P);      // mean eigenvalue (preserved by shrinkage)
    const float inv_s = 1.0f / lam;

    // B0 := A = C_shrunk/lam (spectrum ~ [0.75,1.3] -> NS-safe); B2 := T1 = 1.5I - 0.5A
    #pragma unroll
    for (int j = 0; j < 16; ++j) {
        int f = t + 256 * j;
        int i = f >> 6, jc = f & 63;
        float v = B0[i][jc];
        float sv = ((1.0f - rho) * v + ((i == jc) ? rho * lam : 0.f)) * inv_s;
        B0[i][jc] = sv;
        B2[i][jc] = ((i == jc) ? 1.5f : 0.f) - 0.5f * sv;
    }

    // Newton-Schulz: Y0=A, Z0=I (iter1 folded analytically: Z1=T1, Y1=A*T1)
    mm64f(B1, B0, B2, t, 1.f, 0.f);
    Mat68 Yc = B1, Zc = B2, Tc = B0, U = B3, V = B4;
    #pragma unroll
    for (int it = 0; it < 3; ++it) {
        mm64f(Tc, Zc, Yc, t, -0.5f, 1.5f);   // T = 1.5I - 0.5 Z*Y
        mm64f(U,  Yc, Tc, t, 1.f, 0.f);      // Y' = Y*T
        mm64f(V,  Tc, Zc, t, 1.f, 0.f);      // Z' = T*Z
        Mat68 tmp = Yc; Yc = U; U = tmp;
        tmp = Zc; Zc = V; V = tmp;
    }
    mm64f(Tc, Zc, Yc, t, -0.5f, 1.5f);       // final half-step (only Z needed)
    mm64f(U,  Tc, Zc, t, 1.f, 0.f);          // U = A^{-1/2}
    __syncthreads();

    const float sc = rsqrtf(lam);            // C_shrunk^{-1/2} = A^{-1/2}/sqrt(lam)
    float* sb = shat + (size_t)b * (P * P);
    #pragma unroll
    for (int j = 0; j < 16; ++j) {
        int f = t + 256 * j;
        int i = f >> 6, jc = f & 63;
        sb[f] = U[i][jc] * sc;
    }
    if (t < P) {
        float tv = 0.f;
        #pragma unroll
        for (int d = 0; d < P; ++d) tv += U[t][d] * mus[d];
        tvec[b * P + t] = tv * sc;
    }
}

// ---------------- Kernel C: Z = S_hat * x - (S_hat mu) ----------------
// grid (MM/MT, BB), block 256. LDS = 16KB S + 64KB X tile = 80KB (2 blocks/CU).
__global__ __launch_bounds__(256)
void apply_kernel(const float* __restrict__ x, const float* __restrict__ shat,
                  const float* __restrict__ tvec, float* __restrict__ out)
{
    __shared__ __align__(16) float Ss[P][P];
    __shared__ __align__(16) float Xs[P][MT];
    const int mt = blockIdx.x, b = blockIdx.y;
    const int t = threadIdx.x;
    const float* xb = x + (size_t)b * (P * MM) + mt * MT;
    const float* sb = shat + (size_t)b * (P * P);

    #pragma unroll
    for (int j = 0; j < 4; ++j) {
        int f4 = t + 256 * j;                  // 1024 float4s of S
        int i = f4 >> 4;
        int c = (f4 & 15) * 4;
        *reinterpret_cast<float4*>(&Ss[i][c]) =
            *reinterpret_cast<const float4*>(sb + (size_t)f4 * 4);
    }
    #pragma unroll
    for (int j = 0; j < 16; ++j) {
        int f4 = t + 256 * j;                  // 4096 float4s of X tile
        int r = f4 >> 6;
        int c = (f4 & 63) * 4;
        *reinterpret_cast<float4*>(&Xs[r][c]) =
            *reinterpret_cast<const float4*>(xb + (size_t)r * MM + c);
    }
    __syncthreads();

    const int cg = t >> 4, mg = t & 15;
    const int r0 = cg * 4;
    float acc[4][4][4];
    #pragma unroll
    for (int i = 0; i < 4; ++i)
        #pragma unroll
        for (int q = 0; q < 4; ++q)
            #pragma unroll
            for (int jj = 0; jj < 4; ++jj) acc[i][q][jj] = 0.f;

    for (int d = 0; d < P; ++d) {
        float sv[4];
        *reinterpret_cast<float4*>(sv) = *reinterpret_cast<const float4*>(&Ss[d][r0]); // S sym
        float xv[4][4];
        #pragma unroll
        for (int q = 0; q < 4; ++q)
            *reinterpret_cast<float4*>(xv[q]) =
                *reinterpret_cast<const float4*>(&Xs[d][q * 64 + mg * 4]);
        #pragma unroll
        for (int i = 0; i < 4; ++i)
            #pragma unroll
            for (int q = 0; q < 4; ++q)
                #pragma unroll
                for (int jj = 0; jj < 4; ++jj)
                    acc[i][q][jj] += sv[i] * xv[q][jj];
    }

    float* ob = out + (size_t)b * (P * MM) + mt * MT;
    #pragma unroll
    for (int i = 0; i < 4; ++i) {
        float tv = tvec[b * P + r0 + i];
        #pragma unroll
        for (int q = 0; q < 4; ++q) {
            float4 v = make_float4(acc[i][q][0] - tv, acc[i][q][1] - tv,
                                   acc[i][q][2] - tv, acc[i][q][3] - tv);
            *reinterpret_cast<float4*>(ob + (size_t)(r0 + i) * MM + q * 64 + mg * 4) = v;
        }
    }
}

extern "C" void kernel_launch(void* const* d_in, const int* in_sizes, int n_in,
                              void* d_out, int out_size, void* d_ws, size_t ws_size,
                              hipStream_t stream)
{
    const float* x = (const float*)d_in[0];
    float* out = (float*)d_out;

    // scratch layout (floats): s2p[ns][B][64][64] | s1p[ns][B][64] | shat[B][64][64] | tvec[B][64]
    auto need = [](int ns) -> size_t {
        return ((size_t)ns * BB * P * P + (size_t)ns * BB * P
                + (size_t)BB * P * P + (size_t)BB * P) * sizeof(float);
    };
    int nsplit = 4;
    if (ws_size < need(4)) nsplit = 2;
    if (ws_size < need(2)) nsplit = 1;

    float* s2p  = (float*)d_ws;
    float* s1p  = s2p + (size_t)nsplit * BB * P * P;
    float* shat = s1p + (size_t)nsplit * BB * P;
    float* tvec = shat + (size_t)BB * P * P;

    covpart_kernel<<<dim3(BB, nsplit), 256, 0, stream>>>(x, s2p, s1p, nsplit);
    whiten_kernel<<<dim3(BB), 256, 0, stream>>>(s2p, s1p, shat, tvec, nsplit);
    apply_kernel<<<dim3(MM / MT, BB), 256, 0, stream>>>(x, shat, tvec, out);
}

// Round 3
// 241.581 us; speedup vs baseline: 9.8921x; 9.8921x over previous
//
#include <hip/hip_runtime.h>
#include <hip/hip_bf16.h>

#define BB 256      // batches
#define P 64        // cluster dim
#define MM 4096     // samples per row
#define MC 128      // chunk columns for cov staging
#define MT 256      // tile columns for apply

using bf16x8 = __attribute__((ext_vector_type(8))) short;
using f32x16 = __attribute__((ext_vector_type(16))) float;

__device__ inline unsigned bfh(float a) {           // bf16 RTNE, high 16 bits
    unsigned u = __float_as_uint(a);
    return (u + 0x7fffu + ((u >> 16) & 1u)) >> 16;
}
__device__ inline f32x16 MF(bf16x8 a, bf16x8 b, f32x16 c) {
    return __builtin_amdgcn_mfma_f32_32x32x16_bf16(a, b, c, 0, 0, 0);
}

// ---------------- Kernel A: MFMA bf16-split covariance partials ----------------
// grid (BB, nsplit), 256 thr. C ~= Xh Xh^T + Xh Xl^T + (Xh Xl^T)^T, XlXl^T dropped.
// Symmetric-operand trick: A-frag (row l&31, k 8*(l>>5)+j) == B-frag (col l&31,
// same k) for the same data -> one LDS frag read serves either operand slot.
// Waves own output tiles: w0:{H00,H01} w1:{H11,M00} w2:{M01,M10} w3:{M11};
// accumulate in regs across all chunks, symmetrize via LDS bounce at the end.
__global__ __launch_bounds__(256)
void covpart_kernel(const float* __restrict__ x, float* __restrict__ s2p,
                    float* __restrict__ s1p, int nsplit)
{
    __shared__ __align__(16) unsigned char smem[34816];  // hi[64][136]bf16 | lo  (aliased by 7 f32 tiles)
    char* xh = (char*)smem;
    char* xl = (char*)smem + 17408;

    const int b = blockIdx.x, sp = blockIdx.y;
    const int t = threadIdx.x;
    const int w = t >> 6, l = t & 63;
    const int lr = l & 31, lh = l >> 5;
    const int mlen = MM / nsplit;
    const float* xb = x + (size_t)b * (P * MM) + (size_t)sp * mlen;

    f32x16 accA = {0,0,0,0,0,0,0,0,0,0,0,0,0,0,0,0};
    f32x16 accB = {0,0,0,0,0,0,0,0,0,0,0,0,0,0,0,0};
    float s1a[8] = {0.f,0.f,0.f,0.f,0.f,0.f,0.f,0.f};

    const int kbase = lh * 16;          // byte offset of this lane's k-half in a row

    const int nch = mlen / MC;
    for (int ch = 0; ch < nch; ++ch) {
        const int m0 = ch * MC;
        __syncthreads();
        // ---- stage: 64x128 f32 -> bf16 hi/lo tiles, row sums ride along ----
        float4 v[8];
        #pragma unroll
        for (int j = 0; j < 8; ++j) {
            int f4 = t + 256 * j;
            int r = f4 >> 5, c = (f4 & 31) << 2;
            v[j] = *reinterpret_cast<const float4*>(xb + (size_t)r * MM + m0 + c);
        }
        #pragma unroll
        for (int j = 0; j < 8; ++j) {
            int f4 = t + 256 * j;
            int r = f4 >> 5, c4 = f4 & 31;
            float e0 = v[j].x, e1 = v[j].y, e2 = v[j].z, e3 = v[j].w;
            s1a[j] += (e0 + e1) + (e2 + e3);
            unsigned h0 = bfh(e0), h1 = bfh(e1), h2 = bfh(e2), h3 = bfh(e3);
            float l0 = e0 - __uint_as_float(h0 << 16);
            float l1 = e1 - __uint_as_float(h1 << 16);
            float l2 = e2 - __uint_as_float(h2 << 16);
            float l3 = e3 - __uint_as_float(h3 << 16);
            uint2 hp, lp;
            hp.x = h0 | (h1 << 16);          hp.y = h2 | (h3 << 16);
            lp.x = bfh(l0) | (bfh(l1) << 16); lp.y = bfh(l2) | (bfh(l3) << 16);
            char* dst = xh + r * 272 + c4 * 8;
            *reinterpret_cast<uint2*>(dst) = hp;
            *reinterpret_cast<uint2*>(dst + 17408) = lp;
        }
        __syncthreads();
        // ---- MFMA: 8 k-slices of 16 ----
        #pragma unroll
        for (int ks = 0; ks < 8; ++ks) {
            const int kb = ks * 32 + kbase;
            const char* p0 = xh + lr * 272 + kb;          // rows 0..31 frag
            const char* p1 = xh + (32 + lr) * 272 + kb;   // rows 32..63 frag
            if (w == 0) {
                bf16x8 f0 = *(const bf16x8*)p0;
                bf16x8 f1 = *(const bf16x8*)p1;
                accA = MF(f0, f0, accA);                  // H00
                accB = MF(f0, f1, accB);                  // H01
            } else if (w == 1) {
                bf16x8 f0 = *(const bf16x8*)p0;
                bf16x8 f1 = *(const bf16x8*)p1;
                bf16x8 g0 = *(const bf16x8*)(p0 + 17408);
                accA = MF(f1, f1, accA);                  // H11
                accB = MF(f0, g0, accB);                  // M00
            } else if (w == 2) {
                bf16x8 f0 = *(const bf16x8*)p0;
                bf16x8 f1 = *(const bf16x8*)p1;
                bf16x8 g0 = *(const bf16x8*)(p0 + 17408);
                bf16x8 g1 = *(const bf16x8*)(p1 + 17408);
                accA = MF(f0, g1, accA);                  // M01
                accB = MF(f1, g0, accB);                  // M10
            } else {
                bf16x8 f1 = *(const bf16x8*)p1;
                bf16x8 g1 = *(const bf16x8*)(p1 + 17408);
                accA = MF(f1, g1, accA);                  // M11
            }
        }
    }

    // ---- epilogue: bounce tiles through LDS, symmetrize, store partials ----
    __syncthreads();
    float (*T)[33] = reinterpret_cast<float (*)[33]>(smem);   // [7*32][33] = 29568 B
    const int tb = w * 2;
    #pragma unroll
    for (int n = 0; n < 16; ++n) {
        int row = (n & 3) + 8 * (n >> 2) + 4 * lh;            // verified C/D layout
        T[tb * 32 + row][lr] = accA[n];
        if (w < 3) T[(tb + 1) * 32 + row][lr] = accB[n];
    }
    __syncthreads();
    float* s2b = s2p + ((size_t)sp * BB + b) * (P * P);
    #pragma unroll
    for (int jj = 0; jj < 16; ++jj) {
        int f = t + 256 * jj;
        int rg = f >> 6, cg = f & 63;
        int ri = rg & 31, ci = cg & 31;
        float vv;
        if (rg < 32) {
            if (cg < 32) vv = T[0*32+ri][ci] + T[3*32+ri][ci] + T[3*32+ci][ri];
            else         vv = T[1*32+ri][ci] + T[4*32+ri][ci] + T[5*32+ci][ri];
        } else {
            if (cg < 32) vv = T[1*32+ci][ri] + T[5*32+ri][ci] + T[4*32+ci][ri];
            else         vv = T[2*32+ri][ci] + T[6*32+ri][ci] + T[6*32+ci][ri];
        }
        s2b[f] = vv;
    }
    // ---- s1: reduce per-row partials across the 32 lanes sharing a row set ----
    #pragma unroll
    for (int m = 16; m >= 1; m >>= 1) {
        #pragma unroll
        for (int j = 0; j < 8; ++j) s1a[j] += __shfl_xor(s1a[j], m);
    }
    if ((l & 31) == 0) {
        float* s1b = s1p + ((size_t)sp * BB + b) * P;
        int r0 = 2 * w + lh;
        #pragma unroll
        for (int j = 0; j < 8; ++j) s1b[r0 + 8 * j] = s1a[j];
    }
}

// ---------------- Kernel B: shrinkage + Newton-Schulz inverse sqrt ----------------
typedef float (*Mat68)[68];

__device__ inline void mm64f(Mat68 D, Mat68 A, Mat68 Bm, int t, float alpha, float beta)
{
    __syncthreads();
    const int r0 = (t >> 4) * 4, c0 = (t & 15) * 4;
    float acc[4][4];
    #pragma unroll
    for (int i = 0; i < 4; ++i)
        #pragma unroll
        for (int j = 0; j < 4; ++j) acc[i][j] = 0.f;
    #pragma unroll 4
    for (int k = 0; k < P; ++k) {
        float av[4], bv[4];
        *reinterpret_cast<float4*>(av) = *reinterpret_cast<const float4*>(&A[k][r0]);
        *reinterpret_cast<float4*>(bv) = *reinterpret_cast<const float4*>(&Bm[k][c0]);
        #pragma unroll
        for (int i = 0; i < 4; ++i)
            #pragma unroll
            for (int j = 0; j < 4; ++j) acc[i][j] += av[i] * bv[j];
    }
    __syncthreads();
    #pragma unroll
    for (int i = 0; i < 4; ++i)
        #pragma unroll
        for (int j = 0; j < 4; ++j)
            D[r0 + i][c0 + j] = alpha * acc[i][j] + ((r0 + i) == (c0 + j) ? beta : 0.f);
}

__global__ __launch_bounds__(256)
void whiten_kernel(const float* __restrict__ s2p, const float* __restrict__ s1p,
                   float* __restrict__ shat, float* __restrict__ tvec, int nsplit)
{
    __shared__ __align__(16) float B0[P][68], B1[P][68], B2[P][68], B3[P][68], B4[P][68];
    __shared__ float mus[P];
    __shared__ float red[2][4];
    const int b = blockIdx.x, t = threadIdx.x;

    if (t < P) {
        float s = 0.f;
        for (int sp = 0; sp < nsplit; ++sp) s += s1p[((size_t)sp * BB + b) * P + t];
        mus[t] = s * (1.0f / MM);
    }
    __syncthreads();

    float tr_part = 0.f, s2_part = 0.f;
    #pragma unroll
    for (int j = 0; j < 16; ++j) {
        int f = t + 256 * j;
        int i = f >> 6, jc = f & 63;
        float sum = 0.f;
        for (int sp = 0; sp < nsplit; ++sp)
            sum += s2p[((size_t)sp * BB + b) * (P * P) + f];
        float v = sum * (1.0f / MM) - mus[i] * mus[jc];
        B0[i][jc] = v;
        s2_part += v * v;
        if (i == jc) tr_part += v;
    }
    #pragma unroll
    for (int off = 32; off > 0; off >>= 1) {
        tr_part += __shfl_down(tr_part, off);
        s2_part += __shfl_down(s2_part, off);
    }
    if ((t & 63) == 0) { red[0][t >> 6] = tr_part; red[1][t >> 6] = s2_part; }
    __syncthreads();
    const float trace = red[0][0] + red[0][1] + red[0][2] + red[0][3];
    const float sum2  = red[1][0] + red[1][1] + red[1][2] + red[1][3];

    const float nf = (float)MM;
    const float num = (nf - 2.0f) / nf * sum2 + trace * trace;
    const float den = (nf + 2.0f) * (sum2 - trace * trace / (float)P);
    const float rho = (den > 0.f) ? fminf(num / den, 1.0f) : 1.0f;
    const float lam = trace * (1.0f / P);
    const float inv_s = 1.0f / lam;

    #pragma unroll
    for (int j = 0; j < 16; ++j) {
        int f = t + 256 * j;
        int i = f >> 6, jc = f & 63;
        float v = B0[i][jc];
        float sv = ((1.0f - rho) * v + ((i == jc) ? rho * lam : 0.f)) * inv_s;
        B0[i][jc] = sv;
        B2[i][jc] = ((i == jc) ? 1.5f : 0.f) - 0.5f * sv;
    }

    mm64f(B1, B0, B2, t, 1.f, 0.f);
    Mat68 Yc = B1, Zc = B2, Tc = B0, U = B3, V = B4;
    #pragma unroll
    for (int it = 0; it < 3; ++it) {
        mm64f(Tc, Zc, Yc, t, -0.5f, 1.5f);
        mm64f(U,  Yc, Tc, t, 1.f, 0.f);
        mm64f(V,  Tc, Zc, t, 1.f, 0.f);
        Mat68 tmp = Yc; Yc = U; U = tmp;
        tmp = Zc; Zc = V; V = tmp;
    }
    mm64f(Tc, Zc, Yc, t, -0.5f, 1.5f);
    mm64f(U,  Tc, Zc, t, 1.f, 0.f);
    __syncthreads();

    const float sc = rsqrtf(lam);
    float* sb = shat + (size_t)b * (P * P);
    #pragma unroll
    for (int j = 0; j < 16; ++j) {
        int f = t + 256 * j;
        int i = f >> 6, jc = f & 63;
        sb[f] = U[i][jc] * sc;
    }
    if (t < P) {
        float tv = 0.f;
        #pragma unroll
        for (int d = 0; d < P; ++d) tv += U[t][d] * mus[d];
        tvec[b * P + t] = tv * sc;
    }
}

// ---------------- Kernel C: Z = S_hat * x - (S_hat mu) ----------------
__global__ __launch_bounds__(256)
void apply_kernel(const float* __restrict__ x, const float* __restrict__ shat,
                  const float* __restrict__ tvec, float* __restrict__ out)
{
    __shared__ __align__(16) float Ss[P][P];
    __shared__ __align__(16) float Xs[P][MT];
    const int mt = blockIdx.x, b = blockIdx.y;
    const int t = threadIdx.x;
    const float* xb = x + (size_t)b * (P * MM) + mt * MT;
    const float* sb = shat + (size_t)b * (P * P);

    #pragma unroll
    for (int j = 0; j < 4; ++j) {
        int f4 = t + 256 * j;
        int i = f4 >> 4;
        int c = (f4 & 15) * 4;
        *reinterpret_cast<float4*>(&Ss[i][c]) =
            *reinterpret_cast<const float4*>(sb + (size_t)f4 * 4);
    }
    #pragma unroll
    for (int j = 0; j < 16; ++j) {
        int f4 = t + 256 * j;
        int r = f4 >> 6;
        int c = (f4 & 63) * 4;
        *reinterpret_cast<float4*>(&Xs[r][c]) =
            *reinterpret_cast<const float4*>(xb + (size_t)r * MM + c);
    }
    __syncthreads();

    const int cg = t >> 4, mg = t & 15;
    const int r0 = cg * 4;
    float acc[4][4][4];
    #pragma unroll
    for (int i = 0; i < 4; ++i)
        #pragma unroll
        for (int q = 0; q < 4; ++q)
            #pragma unroll
            for (int jj = 0; jj < 4; ++jj) acc[i][q][jj] = 0.f;

    for (int d = 0; d < P; ++d) {
        float sv[4];
        *reinterpret_cast<float4*>(sv) = *reinterpret_cast<const float4*>(&Ss[d][r0]);
        float xv[4][4];
        #pragma unroll
        for (int q = 0; q < 4; ++q)
            *reinterpret_cast<float4*>(xv[q]) =
                *reinterpret_cast<const float4*>(&Xs[d][q * 64 + mg * 4]);
        #pragma unroll
        for (int i = 0; i < 4; ++i)
            #pragma unroll
            for (int q = 0; q < 4; ++q)
                #pragma unroll
                for (int jj = 0; jj < 4; ++jj)
                    acc[i][q][jj] += sv[i] * xv[q][jj];
    }

    float* ob = out + (size_t)b * (P * MM) + mt * MT;
    #pragma unroll
    for (int i = 0; i < 4; ++i) {
        float tv = tvec[b * P + r0 + i];
        #pragma unroll
        for (int q = 0; q < 4; ++q) {
            float4 v = make_float4(acc[i][q][0] - tv, acc[i][q][1] - tv,
                                   acc[i][q][2] - tv, acc[i][q][3] - tv);
            *reinterpret_cast<float4*>(ob + (size_t)(r0 + i) * MM + q * 64 + mg * 4) = v;
        }
    }
}

extern "C" void kernel_launch(void* const* d_in, const int* in_sizes, int n_in,
                              void* d_out, int out_size, void* d_ws, size_t ws_size,
                              hipStream_t stream)
{
    const float* x = (const float*)d_in[0];
    float* out = (float*)d_out;

    auto need = [](int ns) -> size_t {
        return ((size_t)ns * BB * P * P + (size_t)ns * BB * P
                + (size_t)BB * P * P + (size_t)BB * P) * sizeof(float);
    };
    int nsplit = 4;
    if (ws_size < need(4)) nsplit = 2;
    if (ws_size < need(2)) nsplit = 1;

    float* s2p  = (float*)d_ws;
    float* s1p  = s2p + (size_t)nsplit * BB * P * P;
    float* shat = s1p + (size_t)nsplit * BB * P;
    float* tvec = shat + (size_t)BB * P * P;

    covpart_kernel<<<dim3(BB, nsplit), 256, 0, stream>>>(x, s2p, s1p, nsplit);
    whiten_kernel<<<dim3(BB), 256, 0, stream>>>(s2p, s1p, shat, tvec, nsplit);
    apply_kernel<<<dim3(MM / MT, BB), 256, 0, stream>>>(x, shat, tvec, out);
}

// Round 4
// 236.682 us; speedup vs baseline: 10.0969x; 1.0207x over previous
//
#include <hip/hip_runtime.h>
#include <hip/hip_bf16.h>

#define BB 256      // batches
#define P 64        // cluster dim
#define MM 4096     // samples per row
#define MC 128      // chunk columns for cov staging
#define MT 256      // tile columns for apply

using bf16x8 = __attribute__((ext_vector_type(8))) short;
using f32x16 = __attribute__((ext_vector_type(16))) float;

__device__ inline unsigned bfh(float a) {           // bf16 RTNE, high 16 bits
    unsigned u = __float_as_uint(a);
    return (u + 0x7fffu + ((u >> 16) & 1u)) >> 16;
}
__device__ inline f32x16 MF(bf16x8 a, bf16x8 b, f32x16 c) {
    return __builtin_amdgcn_mfma_f32_32x32x16_bf16(a, b, c, 0, 0, 0);
}

// ---------------- Kernel A: MFMA bf16-split covariance partials ----------------
__global__ __launch_bounds__(256)
void covpart_kernel(const float* __restrict__ x, float* __restrict__ s2p,
                    float* __restrict__ s1p, int nsplit)
{
    __shared__ __align__(16) unsigned char smem[34816];  // hi[64][136]bf16 | lo
    char* xh = (char*)smem;

    const int b = blockIdx.x, sp = blockIdx.y;
    const int t = threadIdx.x;
    const int w = t >> 6, l = t & 63;
    const int lr = l & 31, lh = l >> 5;
    const int mlen = MM / nsplit;
    const float* xb = x + (size_t)b * (P * MM) + (size_t)sp * mlen;

    f32x16 accA = {0,0,0,0,0,0,0,0,0,0,0,0,0,0,0,0};
    f32x16 accB = {0,0,0,0,0,0,0,0,0,0,0,0,0,0,0,0};
    float s1a[8] = {0.f,0.f,0.f,0.f,0.f,0.f,0.f,0.f};

    const int kbase = lh * 16;

    const int nch = mlen / MC;
    for (int ch = 0; ch < nch; ++ch) {
        const int m0 = ch * MC;
        __syncthreads();
        float4 v[8];
        #pragma unroll
        for (int j = 0; j < 8; ++j) {
            int f4 = t + 256 * j;
            int r = f4 >> 5, c = (f4 & 31) << 2;
            v[j] = *reinterpret_cast<const float4*>(xb + (size_t)r * MM + m0 + c);
        }
        #pragma unroll
        for (int j = 0; j < 8; ++j) {
            int f4 = t + 256 * j;
            int r = f4 >> 5, c4 = f4 & 31;
            float e0 = v[j].x, e1 = v[j].y, e2 = v[j].z, e3 = v[j].w;
            s1a[j] += (e0 + e1) + (e2 + e3);
            unsigned h0 = bfh(e0), h1 = bfh(e1), h2 = bfh(e2), h3 = bfh(e3);
            float l0 = e0 - __uint_as_float(h0 << 16);
            float l1 = e1 - __uint_as_float(h1 << 16);
            float l2 = e2 - __uint_as_float(h2 << 16);
            float l3 = e3 - __uint_as_float(h3 << 16);
            uint2 hp, lp;
            hp.x = h0 | (h1 << 16);          hp.y = h2 | (h3 << 16);
            lp.x = bfh(l0) | (bfh(l1) << 16); lp.y = bfh(l2) | (bfh(l3) << 16);
            char* dst = xh + r * 272 + c4 * 8;
            *reinterpret_cast<uint2*>(dst) = hp;
            *reinterpret_cast<uint2*>(dst + 17408) = lp;
        }
        __syncthreads();
        #pragma unroll
        for (int ks = 0; ks < 8; ++ks) {
            const int kb = ks * 32 + kbase;
            const char* p0 = xh + lr * 272 + kb;
            const char* p1 = xh + (32 + lr) * 272 + kb;
            if (w == 0) {
                bf16x8 f0 = *(const bf16x8*)p0;
                bf16x8 f1 = *(const bf16x8*)p1;
                accA = MF(f0, f0, accA);                  // H00
                accB = MF(f0, f1, accB);                  // H01
            } else if (w == 1) {
                bf16x8 f0 = *(const bf16x8*)p0;
                bf16x8 f1 = *(const bf16x8*)p1;
                bf16x8 g0 = *(const bf16x8*)(p0 + 17408);
                accA = MF(f1, f1, accA);                  // H11
                accB = MF(f0, g0, accB);                  // M00
            } else if (w == 2) {
                bf16x8 f0 = *(const bf16x8*)p0;
                bf16x8 f1 = *(const bf16x8*)p1;
                bf16x8 g0 = *(const bf16x8*)(p0 + 17408);
                bf16x8 g1 = *(const bf16x8*)(p1 + 17408);
                accA = MF(f0, g1, accA);                  // M01
                accB = MF(f1, g0, accB);                  // M10
            } else {
                bf16x8 f1 = *(const bf16x8*)p1;
                bf16x8 g1 = *(const bf16x8*)(p1 + 17408);
                accA = MF(f1, g1, accA);                  // M11
            }
        }
    }

    __syncthreads();
    float (*T)[33] = reinterpret_cast<float (*)[33]>(smem);
    const int tb = w * 2;
    #pragma unroll
    for (int n = 0; n < 16; ++n) {
        int row = (n & 3) + 8 * (n >> 2) + 4 * lh;
        T[tb * 32 + row][lr] = accA[n];
        if (w < 3) T[(tb + 1) * 32 + row][lr] = accB[n];
    }
    __syncthreads();
    float* s2b = s2p + ((size_t)sp * BB + b) * (P * P);
    #pragma unroll
    for (int jj = 0; jj < 16; ++jj) {
        int f = t + 256 * jj;
        int rg = f >> 6, cg = f & 63;
        int ri = rg & 31, ci = cg & 31;
        float vv;
        if (rg < 32) {
            if (cg < 32) vv = T[0*32+ri][ci] + T[3*32+ri][ci] + T[3*32+ci][ri];
            else         vv = T[1*32+ri][ci] + T[4*32+ri][ci] + T[5*32+ci][ri];
        } else {
            if (cg < 32) vv = T[1*32+ci][ri] + T[5*32+ri][ci] + T[4*32+ci][ri];
            else         vv = T[2*32+ri][ci] + T[6*32+ri][ci] + T[6*32+ci][ri];
        }
        s2b[f] = vv;
    }
    #pragma unroll
    for (int m = 16; m >= 1; m >>= 1) {
        #pragma unroll
        for (int j = 0; j < 8; ++j) s1a[j] += __shfl_xor(s1a[j], m);
    }
    if ((l & 31) == 0) {
        float* s1b = s1p + ((size_t)sp * BB + b) * P;
        int r0 = 2 * w + lh;
        #pragma unroll
        for (int j = 0; j < 8; ++j) s1b[r0 + 8 * j] = s1a[j];
    }
}

// ---------------- Kernel B: shrinkage + Newton-Schulz inverse sqrt ----------------
typedef float (*Mat68)[68];

__device__ inline void mm64f(Mat68 D, Mat68 A, Mat68 Bm, int t, float alpha, float beta)
{
    __syncthreads();
    const int r0 = (t >> 4) * 4, c0 = (t & 15) * 4;
    float acc[4][4];
    #pragma unroll
    for (int i = 0; i < 4; ++i)
        #pragma unroll
        for (int j = 0; j < 4; ++j) acc[i][j] = 0.f;
    #pragma unroll 4
    for (int k = 0; k < P; ++k) {
        float av[4], bv[4];
        *reinterpret_cast<float4*>(av) = *reinterpret_cast<const float4*>(&A[k][r0]);
        *reinterpret_cast<float4*>(bv) = *reinterpret_cast<const float4*>(&Bm[k][c0]);
        #pragma unroll
        for (int i = 0; i < 4; ++i)
            #pragma unroll
            for (int j = 0; j < 4; ++j) acc[i][j] += av[i] * bv[j];
    }
    __syncthreads();
    #pragma unroll
    for (int i = 0; i < 4; ++i)
        #pragma unroll
        for (int j = 0; j < 4; ++j)
            D[r0 + i][c0 + j] = alpha * acc[i][j] + ((r0 + i) == (c0 + j) ? beta : 0.f);
}

__global__ __launch_bounds__(256)
void whiten_kernel(const float* __restrict__ s2p, const float* __restrict__ s1p,
                   float* __restrict__ shat, float* __restrict__ tvec, int nsplit)
{
    __shared__ __align__(16) float B0[P][68], B1[P][68], B2[P][68], B3[P][68], B4[P][68];
    __shared__ float mus[P];
    __shared__ float red[2][4];
    const int b = blockIdx.x, t = threadIdx.x;

    if (t < P) {
        float s = 0.f;
        for (int sp = 0; sp < nsplit; ++sp) s += s1p[((size_t)sp * BB + b) * P + t];
        mus[t] = s * (1.0f / MM);
    }
    __syncthreads();

    float tr_part = 0.f, s2_part = 0.f;
    #pragma unroll
    for (int j = 0; j < 16; ++j) {
        int f = t + 256 * j;
        int i = f >> 6, jc = f & 63;
        float sum = 0.f;
        for (int sp = 0; sp < nsplit; ++sp)
            sum += s2p[((size_t)sp * BB + b) * (P * P) + f];
        float v = sum * (1.0f / MM) - mus[i] * mus[jc];
        B0[i][jc] = v;
        s2_part += v * v;
        if (i == jc) tr_part += v;
    }
    #pragma unroll
    for (int off = 32; off > 0; off >>= 1) {
        tr_part += __shfl_down(tr_part, off);
        s2_part += __shfl_down(s2_part, off);
    }
    if ((t & 63) == 0) { red[0][t >> 6] = tr_part; red[1][t >> 6] = s2_part; }
    __syncthreads();
    const float trace = red[0][0] + red[0][1] + red[0][2] + red[0][3];
    const float sum2  = red[1][0] + red[1][1] + red[1][2] + red[1][3];

    const float nf = (float)MM;
    const float num = (nf - 2.0f) / nf * sum2 + trace * trace;
    const float den = (nf + 2.0f) * (sum2 - trace * trace / (float)P);
    const float rho = (den > 0.f) ? fminf(num / den, 1.0f) : 1.0f;
    const float lam = trace * (1.0f / P);
    const float inv_s = 1.0f / lam;

    #pragma unroll
    for (int j = 0; j < 16; ++j) {
        int f = t + 256 * j;
        int i = f >> 6, jc = f & 63;
        float v = B0[i][jc];
        float sv = ((1.0f - rho) * v + ((i == jc) ? rho * lam : 0.f)) * inv_s;
        B0[i][jc] = sv;
        B2[i][jc] = ((i == jc) ? 1.5f : 0.f) - 0.5f * sv;
    }

    // Newton-Schulz, 3 maps total (spectrum of A within [0.73,1.27] even at
    // rho=0 -> 3-map eigenvalue error <= 6e-6, far below one output bf16 ulp).
    mm64f(B1, B0, B2, t, 1.f, 0.f);          // map1: Y1=A*T1, Z1=T1
    Mat68 Yc = B1, Zc = B2, Tc = B0, U = B3, V = B4;
    {
        mm64f(Tc, Zc, Yc, t, -0.5f, 1.5f);   // map2: T=1.5I-0.5*Z1*Y1
        mm64f(U,  Yc, Tc, t, 1.f, 0.f);      // Y2=Y1*T
        mm64f(V,  Tc, Zc, t, 1.f, 0.f);      // Z2=T*Z1
        Mat68 tmp = Yc; Yc = U; U = tmp;
        tmp = Zc; Zc = V; V = tmp;
    }
    mm64f(Tc, Zc, Yc, t, -0.5f, 1.5f);       // map3: T=1.5I-0.5*Z2*Y2
    mm64f(U,  Tc, Zc, t, 1.f, 0.f);          // U = T*Z2 = A^{-1/2}
    __syncthreads();

    const float sc = rsqrtf(lam);
    float* sb = shat + (size_t)b * (P * P);
    #pragma unroll
    for (int j = 0; j < 16; ++j) {
        int f = t + 256 * j;
        int i = f >> 6, jc = f & 63;
        sb[f] = U[i][jc] * sc;
    }
    if (t < P) {
        float tv = 0.f;
        #pragma unroll
        for (int d = 0; d < P; ++d) tv += U[t][d] * mus[d];
        tvec[b * P + t] = tv * sc;
    }
}

// ---------------- Kernel C: Z = S_hat * x - (S_hat mu) ----------------
// 8x8 register blocking: 4 ds_read_b128 per 64 FMAs (was 5 per 64).
__global__ __launch_bounds__(256)
void apply_kernel(const float* __restrict__ x, const float* __restrict__ shat,
                  const float* __restrict__ tvec, float* __restrict__ out)
{
    __shared__ __align__(16) float Ss[P][P];
    __shared__ __align__(16) float Xs[P][MT];
    const int mt = blockIdx.x, b = blockIdx.y;
    const int t = threadIdx.x;
    const float* xb = x + (size_t)b * (P * MM) + mt * MT;
    const float* sb = shat + (size_t)b * (P * P);

    #pragma unroll
    for (int j = 0; j < 4; ++j) {
        int f4 = t + 256 * j;
        *reinterpret_cast<float4*>(&Ss[f4 >> 4][(f4 & 15) * 4]) =
            *reinterpret_cast<const float4*>(sb + (size_t)f4 * 4);
    }
    #pragma unroll
    for (int j = 0; j < 16; ++j) {
        int f4 = t + 256 * j;
        int r = f4 >> 6, c = (f4 & 63) * 4;
        *reinterpret_cast<float4*>(&Xs[r][c]) =
            *reinterpret_cast<const float4*>(xb + (size_t)r * MM + c);
    }
    __syncthreads();

    const int r0 = (t >> 5) * 8;     // 8 row-groups
    const int c0 = (t & 31) * 8;     // 32 col-groups
    float acc[8][8];
    #pragma unroll
    for (int i = 0; i < 8; ++i)
        #pragma unroll
        for (int j = 0; j < 8; ++j) acc[i][j] = 0.f;

    for (int d = 0; d < P; ++d) {
        float sv[8], xv[8];
        *reinterpret_cast<float4*>(&sv[0]) = *reinterpret_cast<const float4*>(&Ss[d][r0]);     // S sym
        *reinterpret_cast<float4*>(&sv[4]) = *reinterpret_cast<const float4*>(&Ss[d][r0 + 4]);
        *reinterpret_cast<float4*>(&xv[0]) = *reinterpret_cast<const float4*>(&Xs[d][c0]);
        *reinterpret_cast<float4*>(&xv[4]) = *reinterpret_cast<const float4*>(&Xs[d][c0 + 4]);
        #pragma unroll
        for (int i = 0; i < 8; ++i)
            #pragma unroll
            for (int j = 0; j < 8; ++j)
                acc[i][j] += sv[i] * xv[j];
    }

    float tv[8];
    *reinterpret_cast<float4*>(&tv[0]) = *reinterpret_cast<const float4*>(tvec + b * P + r0);
    *reinterpret_cast<float4*>(&tv[4]) = *reinterpret_cast<const float4*>(tvec + b * P + r0 + 4);
    float* ob = out + (size_t)b * (P * MM) + mt * MT + c0;
    #pragma unroll
    for (int i = 0; i < 8; ++i) {
        float4 v0 = make_float4(acc[i][0] - tv[i], acc[i][1] - tv[i],
                                acc[i][2] - tv[i], acc[i][3] - tv[i]);
        float4 v1 = make_float4(acc[i][4] - tv[i], acc[i][5] - tv[i],
                                acc[i][6] - tv[i], acc[i][7] - tv[i]);
        *reinterpret_cast<float4*>(ob + (size_t)(r0 + i) * MM)     = v0;
        *reinterpret_cast<float4*>(ob + (size_t)(r0 + i) * MM + 4) = v1;
    }
}

extern "C" void kernel_launch(void* const* d_in, const int* in_sizes, int n_in,
                              void* d_out, int out_size, void* d_ws, size_t ws_size,
                              hipStream_t stream)
{
    const float* x = (const float*)d_in[0];
    float* out = (float*)d_out;

    auto need = [](int ns) -> size_t {
        return ((size_t)ns * BB * P * P + (size_t)ns * BB * P
                + (size_t)BB * P * P + (size_t)BB * P) * sizeof(float);
    };
    int nsplit = 4;
    if (ws_size < need(4)) nsplit = 2;
    if (ws_size < need(2)) nsplit = 1;

    float* s2p  = (float*)d_ws;
    float* s1p  = s2p + (size_t)nsplit * BB * P * P;
    float* shat = s1p + (size_t)nsplit * BB * P;
    float* tvec = shat + (size_t)BB * P * P;

    covpart_kernel<<<dim3(BB, nsplit), 256, 0, stream>>>(x, s2p, s1p, nsplit);
    whiten_kernel<<<dim3(BB), 256, 0, stream>>>(s2p, s1p, shat, tvec, nsplit);
    apply_kernel<<<dim3(MM / MT, BB), 256, 0, stream>>>(x, shat, tvec, out);
}

// Round 5
// 215.831 us; speedup vs baseline: 11.0723x; 1.0966x over previous
//
#include <hip/hip_runtime.h>
#include <hip/hip_bf16.h>

#define BB 256      // batches
#define P 64        // cluster dim
#define MM 4096     // samples per row
#define MC 128      // chunk columns for cov staging
#define MT 256      // tile columns for apply

using bf16x8 = __attribute__((ext_vector_type(8))) short;
using f32x16 = __attribute__((ext_vector_type(16))) float;

__device__ inline unsigned bfh(float a) {           // bf16 RTNE, high 16 bits
    unsigned u = __float_as_uint(a);
    return (u + 0x7fffu + ((u >> 16) & 1u)) >> 16;
}
__device__ inline f32x16 MF(bf16x8 a, bf16x8 b, f32x16 c) {
    return __builtin_amdgcn_mfma_f32_32x32x16_bf16(a, b, c, 0, 0, 0);
}

// ---------------- Kernel A: pure-bf16 MFMA covariance partials ----------------
// grid (BB, nsplit), 256 thr. C ~= Xh Xh^T (bf16 rounding of x gives ~1e-3
// relative perturbation of C -> ~3e-3 on Z, well under threshold margin).
// k-split across waves: wave w handles k-slices {2w, 2w+1} of each chunk,
// computing partial H00/H01/H11; cross-wave sum in the epilogue.
__global__ __launch_bounds__(256)
void covpart_kernel(const float* __restrict__ x, float* __restrict__ s2p,
                    float* __restrict__ s1p, int nsplit)
{
    __shared__ __align__(16) unsigned char smem[17408];  // hi[64][136] bf16
    char* xh = (char*)smem;

    const int b = blockIdx.x, sp = blockIdx.y;
    const int t = threadIdx.x;
    const int w = t >> 6, l = t & 63;
    const int lr = l & 31, lh = l >> 5;
    const int mlen = MM / nsplit;
    const float* xb = x + (size_t)b * (P * MM) + (size_t)sp * mlen;

    f32x16 acc0 = {0,0,0,0,0,0,0,0,0,0,0,0,0,0,0,0};   // H00 partial
    f32x16 acc1 = {0,0,0,0,0,0,0,0,0,0,0,0,0,0,0,0};   // H01 partial
    f32x16 acc2 = {0,0,0,0,0,0,0,0,0,0,0,0,0,0,0,0};   // H11 partial
    float s1a[8] = {0.f,0.f,0.f,0.f,0.f,0.f,0.f,0.f};

    const int kbase = lh * 16;          // byte offset of lane's k-half in a slice

    const int nch = mlen / MC;
    for (int ch = 0; ch < nch; ++ch) {
        const int m0 = ch * MC;
        __syncthreads();
        float4 v[8];
        #pragma unroll
        for (int j = 0; j < 8; ++j) {
            int f4 = t + 256 * j;
            int r = f4 >> 5, c = (f4 & 31) << 2;
            v[j] = *reinterpret_cast<const float4*>(xb + (size_t)r * MM + m0 + c);
        }
        #pragma unroll
        for (int j = 0; j < 8; ++j) {
            int f4 = t + 256 * j;
            int r = f4 >> 5, c4 = f4 & 31;
            float e0 = v[j].x, e1 = v[j].y, e2 = v[j].z, e3 = v[j].w;
            s1a[j] += (e0 + e1) + (e2 + e3);
            uint2 hp;
            hp.x = bfh(e0) | (bfh(e1) << 16);
            hp.y = bfh(e2) | (bfh(e3) << 16);
            *reinterpret_cast<uint2*>(xh + r * 272 + c4 * 8) = hp;
        }
        __syncthreads();
        #pragma unroll
        for (int kk = 0; kk < 2; ++kk) {
            const int kb = (2 * w + kk) * 32 + kbase;
            bf16x8 f0 = *(const bf16x8*)(xh + lr * 272 + kb);
            bf16x8 f1 = *(const bf16x8*)(xh + (32 + lr) * 272 + kb);
            acc0 = MF(f0, f0, acc0);
            acc1 = MF(f0, f1, acc1);
            acc2 = MF(f1, f1, acc2);
        }
    }

    // ---- epilogue: cross-wave partial reduction via LDS, 3 passes ----
    float (*T)[32][33] = reinterpret_cast<float (*)[32][33]>(smem);  // 16.9 KB
    float* s2b = s2p + ((size_t)sp * BB + b) * (P * P);

#define REDUCE_PASS(ACC, STORE)                                       \
    {                                                                 \
        __syncthreads();                                              \
        _Pragma("unroll")                                             \
        for (int n = 0; n < 16; ++n) {                                \
            int row = (n & 3) + 8 * (n >> 2) + 4 * lh;                \
            T[w][row][lr] = ACC[n];                                   \
        }                                                             \
        __syncthreads();                                              \
        _Pragma("unroll")                                             \
        for (int q = 0; q < 4; ++q) {                                 \
            int idx = t + 256 * q;                                    \
            int r = idx >> 5, c = idx & 31;                           \
            float s = T[0][r][c] + T[1][r][c] + T[2][r][c] + T[3][r][c]; \
            STORE                                                     \
        }                                                             \
    }

    REDUCE_PASS(acc0, s2b[r * 64 + c] = s;)
    REDUCE_PASS(acc1, s2b[r * 64 + 32 + c] = s; s2b[(32 + c) * 64 + r] = s;)
    REDUCE_PASS(acc2, s2b[(32 + r) * 64 + 32 + c] = s;)
#undef REDUCE_PASS

    // ---- s1 row sums: reduce across the 32 lanes sharing a row set ----
    #pragma unroll
    for (int m = 16; m >= 1; m >>= 1) {
        #pragma unroll
        for (int j = 0; j < 8; ++j) s1a[j] += __shfl_xor(s1a[j], m);
    }
    if ((l & 31) == 0) {
        float* s1b = s1p + ((size_t)sp * BB + b) * P;
        int r0 = 2 * w + lh;
        #pragma unroll
        for (int j = 0; j < 8; ++j) s1b[r0 + 8 * j] = s1a[j];
    }
}

// ---------------- Kernel B: shrinkage + Newton-Schulz inverse sqrt ----------------
typedef float (*Mat68)[68];

__device__ inline void mm64f(Mat68 D, Mat68 A, Mat68 Bm, int t, float alpha, float beta)
{
    __syncthreads();
    const int r0 = (t >> 4) * 4, c0 = (t & 15) * 4;
    float acc[4][4];
    #pragma unroll
    for (int i = 0; i < 4; ++i)
        #pragma unroll
        for (int j = 0; j < 4; ++j) acc[i][j] = 0.f;
    #pragma unroll 4
    for (int k = 0; k < P; ++k) {
        float av[4], bv[4];
        *reinterpret_cast<float4*>(av) = *reinterpret_cast<const float4*>(&A[k][r0]);
        *reinterpret_cast<float4*>(bv) = *reinterpret_cast<const float4*>(&Bm[k][c0]);
        #pragma unroll
        for (int i = 0; i < 4; ++i)
            #pragma unroll
            for (int j = 0; j < 4; ++j) acc[i][j] += av[i] * bv[j];
    }
    __syncthreads();
    #pragma unroll
    for (int i = 0; i < 4; ++i)
        #pragma unroll
        for (int j = 0; j < 4; ++j)
            D[r0 + i][c0 + j] = alpha * acc[i][j] + ((r0 + i) == (c0 + j) ? beta : 0.f);
}

__global__ __launch_bounds__(256)
void whiten_kernel(const float* __restrict__ s2p, const float* __restrict__ s1p,
                   float* __restrict__ shat, float* __restrict__ tvec, int nsplit)
{
    __shared__ __align__(16) float B0[P][68], B1[P][68], B2[P][68], B3[P][68], B4[P][68];
    __shared__ float mus[P];
    __shared__ float red[2][4];
    const int b = blockIdx.x, t = threadIdx.x;

    if (t < P) {
        float s = 0.f;
        for (int sp = 0; sp < nsplit; ++sp) s += s1p[((size_t)sp * BB + b) * P + t];
        mus[t] = s * (1.0f / MM);
    }
    __syncthreads();

    float tr_part = 0.f, s2_part = 0.f;
    #pragma unroll
    for (int j = 0; j < 16; ++j) {
        int f = t + 256 * j;
        int i = f >> 6, jc = f & 63;
        float sum = 0.f;
        for (int sp = 0; sp < nsplit; ++sp)
            sum += s2p[((size_t)sp * BB + b) * (P * P) + f];
        float v = sum * (1.0f / MM) - mus[i] * mus[jc];
        B0[i][jc] = v;
        s2_part += v * v;
        if (i == jc) tr_part += v;
    }
    #pragma unroll
    for (int off = 32; off > 0; off >>= 1) {
        tr_part += __shfl_down(tr_part, off);
        s2_part += __shfl_down(s2_part, off);
    }
    if ((t & 63) == 0) { red[0][t >> 6] = tr_part; red[1][t >> 6] = s2_part; }
    __syncthreads();
    const float trace = red[0][0] + red[0][1] + red[0][2] + red[0][3];
    const float sum2  = red[1][0] + red[1][1] + red[1][2] + red[1][3];

    const float nf = (float)MM;
    const float num = (nf - 2.0f) / nf * sum2 + trace * trace;
    const float den = (nf + 2.0f) * (sum2 - trace * trace / (float)P);
    const float rho = (den > 0.f) ? fminf(num / den, 1.0f) : 1.0f;
    const float lam = trace * (1.0f / P);
    const float inv_s = 1.0f / lam;

    #pragma unroll
    for (int j = 0; j < 16; ++j) {
        int f = t + 256 * j;
        int i = f >> 6, jc = f & 63;
        float v = B0[i][jc];
        float sv = ((1.0f - rho) * v + ((i == jc) ? rho * lam : 0.f)) * inv_s;
        B0[i][jc] = sv;
        B2[i][jc] = ((i == jc) ? 1.5f : 0.f) - 0.5f * sv;
    }

    // Newton-Schulz, 3 maps (spectrum in [0.73,1.27] -> error ~6e-6)
    mm64f(B1, B0, B2, t, 1.f, 0.f);          // map1: Y1=A*T1, Z1=T1
    Mat68 Yc = B1, Zc = B2, Tc = B0, U = B3, V = B4;
    {
        mm64f(Tc, Zc, Yc, t, -0.5f, 1.5f);   // map2
        mm64f(U,  Yc, Tc, t, 1.f, 0.f);
        mm64f(V,  Tc, Zc, t, 1.f, 0.f);
        Mat68 tmp = Yc; Yc = U; U = tmp;
        tmp = Zc; Zc = V; V = tmp;
    }
    mm64f(Tc, Zc, Yc, t, -0.5f, 1.5f);       // map3
    mm64f(U,  Tc, Zc, t, 1.f, 0.f);          // U = A^{-1/2}
    __syncthreads();

    const float sc = rsqrtf(lam);
    float* sb = shat + (size_t)b * (P * P);
    #pragma unroll
    for (int j = 0; j < 16; ++j) {
        int f = t + 256 * j;
        int i = f >> 6, jc = f & 63;
        sb[f] = U[i][jc] * sc;
    }
    if (t < P) {
        float tv = 0.f;
        #pragma unroll
        for (int d = 0; d < P; ++d) tv += U[t][d] * mus[d];
        tvec[b * P + t] = tv * sc;
    }
}

// ---------------- Kernel C: Z = S_hat * x - (S_hat mu) ----------------
// 8x8 register blocking, wave-quadrant mapping: all LDS read patterns are
// <=16 distinct addresses per instr (2-way / broadcast = conflict-free).
__global__ __launch_bounds__(256)
void apply_kernel(const float* __restrict__ x, const float* __restrict__ shat,
                  const float* __restrict__ tvec, float* __restrict__ out)
{
    __shared__ __align__(16) float Ss[P][P];
    __shared__ __align__(16) float Xs[P][MT];
    const int mt = blockIdx.x, b = blockIdx.y;
    const int t = threadIdx.x;
    const float* xb = x + (size_t)b * (P * MM) + mt * MT;
    const float* sb = shat + (size_t)b * (P * P);

    #pragma unroll
    for (int j = 0; j < 4; ++j) {
        int f4 = t + 256 * j;
        *reinterpret_cast<float4*>(&Ss[f4 >> 4][(f4 & 15) * 4]) =
            *reinterpret_cast<const float4*>(sb + (size_t)f4 * 4);
    }
    #pragma unroll
    for (int j = 0; j < 16; ++j) {
        int f4 = t + 256 * j;
        int r = f4 >> 6, c = (f4 & 63) * 4;
        *reinterpret_cast<float4*>(&Xs[r][c]) =
            *reinterpret_cast<const float4*>(xb + (size_t)r * MM + c);
    }
    __syncthreads();

    const int w = t >> 6, l = t & 63;
    const int r0 = (w & 1) * 32 + (l >> 4) * 8;      // rows r0..r0+7
    const int c0 = (w >> 1) * 128 + (l & 15) * 4;    // cols c0..c0+3, c0+64..+67
    float acc[8][8];
    #pragma unroll
    for (int i = 0; i < 8; ++i)
        #pragma unroll
        for (int j = 0; j < 8; ++j) acc[i][j] = 0.f;

    for (int d = 0; d < P; ++d) {
        float sv[8], xv[8];
        *reinterpret_cast<float4*>(&sv[0]) = *reinterpret_cast<const float4*>(&Ss[d][r0]);      // S sym
        *reinterpret_cast<float4*>(&sv[4]) = *reinterpret_cast<const float4*>(&Ss[d][r0 + 4]);
        *reinterpret_cast<float4*>(&xv[0]) = *reinterpret_cast<const float4*>(&Xs[d][c0]);
        *reinterpret_cast<float4*>(&xv[4]) = *reinterpret_cast<const float4*>(&Xs[d][c0 + 64]);
        #pragma unroll
        for (int i = 0; i < 8; ++i)
            #pragma unroll
            for (int j = 0; j < 8; ++j)
                acc[i][j] += sv[i] * xv[j];
    }

    float tv[8];
    *reinterpret_cast<float4*>(&tv[0]) = *reinterpret_cast<const float4*>(tvec + b * P + r0);
    *reinterpret_cast<float4*>(&tv[4]) = *reinterpret_cast<const float4*>(tvec + b * P + r0 + 4);
    float* ob = out + (size_t)b * (P * MM) + mt * MT;
    #pragma unroll
    for (int i = 0; i < 8; ++i) {
        float4 v0 = make_float4(acc[i][0] - tv[i], acc[i][1] - tv[i],
                                acc[i][2] - tv[i], acc[i][3] - tv[i]);
        float4 v1 = make_float4(acc[i][4] - tv[i], acc[i][5] - tv[i],
                                acc[i][6] - tv[i], acc[i][7] - tv[i]);
        *reinterpret_cast<float4*>(ob + (size_t)(r0 + i) * MM + c0)      = v0;
        *reinterpret_cast<float4*>(ob + (size_t)(r0 + i) * MM + c0 + 64) = v1;
    }
}

extern "C" void kernel_launch(void* const* d_in, const int* in_sizes, int n_in,
                              void* d_out, int out_size, void* d_ws, size_t ws_size,
                              hipStream_t stream)
{
    const float* x = (const float*)d_in[0];
    float* out = (float*)d_out;

    auto need = [](int ns) -> size_t {
        return ((size_t)ns * BB * P * P + (size_t)ns * BB * P
                + (size_t)BB * P * P + (size_t)BB * P) * sizeof(float);
    };
    int nsplit = 4;
    if (ws_size < need(4)) nsplit = 2;
    if (ws_size < need(2)) nsplit = 1;

    float* s2p  = (float*)d_ws;
    float* s1p  = s2p + (size_t)nsplit * BB * P * P;
    float* shat = s1p + (size_t)nsplit * BB * P;
    float* tvec = shat + (size_t)BB * P * P;

    covpart_kernel<<<dim3(BB, nsplit), 256, 0, stream>>>(x, s2p, s1p, nsplit);
    whiten_kernel<<<dim3(BB), 256, 0, stream>>>(s2p, s1p, shat, tvec, nsplit);
    apply_kernel<<<dim3(MM / MT, BB), 256, 0, stream>>>(x, shat, tvec, out);
}

// Round 6
// 196.183 us; speedup vs baseline: 12.1812x; 1.1002x over previous
//
#include <hip/hip_runtime.h>
#include <hip/hip_bf16.h>

#define BB 256      // batches
#define P 64        // cluster dim
#define MM 4096     // samples per row
#define MC 128      // chunk columns for cov staging
#define MT 256      // tile columns for apply

using bf16x8 = __attribute__((ext_vector_type(8))) short;
using f32x16 = __attribute__((ext_vector_type(16))) float;

__device__ inline f32x16 MF(bf16x8 a, bf16x8 b, f32x16 c) {
    return __builtin_amdgcn_mfma_f32_32x32x16_bf16(a, b, c, 0, 0, 0);
}
__device__ inline unsigned cvtpk(float lo, float hi) {   // {bf16(lo), bf16(hi)} RTNE
    unsigned u;
    asm("v_cvt_pk_bf16_f32 %0, %1, %2" : "=v"(u) : "v"(lo), "v"(hi));
    return u;
}

// ---------------- Kernel A: pure-bf16 MFMA covariance partials ----------------
// grid (BB, nsplit), 256 thr. k-split across waves; cross-wave sum in epilogue.
__global__ __launch_bounds__(256)
void covpart_kernel(const float* __restrict__ x, float* __restrict__ s2p,
                    float* __restrict__ s1p, int nsplit)
{
    __shared__ __align__(16) unsigned char smem[17408];  // hi[64][136] bf16
    char* xh = (char*)smem;

    const int b = blockIdx.x, sp = blockIdx.y;
    const int t = threadIdx.x;
    const int w = t >> 6, l = t & 63;
    const int lr = l & 31, lh = l >> 5;
    const int mlen = MM / nsplit;
    const float* xb = x + (size_t)b * (P * MM) + (size_t)sp * mlen;

    f32x16 acc0 = {0,0,0,0,0,0,0,0,0,0,0,0,0,0,0,0};   // H00 partial
    f32x16 acc1 = {0,0,0,0,0,0,0,0,0,0,0,0,0,0,0,0};   // H01 partial
    f32x16 acc2 = {0,0,0,0,0,0,0,0,0,0,0,0,0,0,0,0};   // H11 partial
    float s1a[8] = {0.f,0.f,0.f,0.f,0.f,0.f,0.f,0.f};

    const int kbase = lh * 16;          // byte offset of lane's k-half in a slice

    const int nch = mlen / MC;
    for (int ch = 0; ch < nch; ++ch) {
        const int m0 = ch * MC;
        __syncthreads();
        float4 v[8];
        #pragma unroll
        for (int j = 0; j < 8; ++j) {
            int f4 = t + 256 * j;
            int r = f4 >> 5, c = (f4 & 31) << 2;
            v[j] = *reinterpret_cast<const float4*>(xb + (size_t)r * MM + m0 + c);
        }
        #pragma unroll
        for (int j = 0; j < 8; ++j) {
            int f4 = t + 256 * j;
            int r = f4 >> 5, c4 = f4 & 31;
            float e0 = v[j].x, e1 = v[j].y, e2 = v[j].z, e3 = v[j].w;
            s1a[j] += (e0 + e1) + (e2 + e3);
            uint2 hp;
            hp.x = cvtpk(e0, e1);
            hp.y = cvtpk(e2, e3);
            *reinterpret_cast<uint2*>(xh + r * 272 + c4 * 8) = hp;
        }
        __syncthreads();
        #pragma unroll
        for (int kk = 0; kk < 2; ++kk) {
            const int kb = (2 * w + kk) * 32 + kbase;
            bf16x8 f0 = *(const bf16x8*)(xh + lr * 272 + kb);
            bf16x8 f1 = *(const bf16x8*)(xh + (32 + lr) * 272 + kb);
            acc0 = MF(f0, f0, acc0);
            acc1 = MF(f0, f1, acc1);
            acc2 = MF(f1, f1, acc2);
        }
    }

    // ---- epilogue: cross-wave partial reduction via LDS, 3 passes ----
    float (*T)[32][33] = reinterpret_cast<float (*)[32][33]>(smem);  // 16.9 KB
    float* s2b = s2p + ((size_t)sp * BB + b) * (P * P);

#define REDUCE_PASS(ACC, STORE)                                       \
    {                                                                 \
        __syncthreads();                                              \
        _Pragma("unroll")                                             \
        for (int n = 0; n < 16; ++n) {                                \
            int row = (n & 3) + 8 * (n >> 2) + 4 * lh;                \
            T[w][row][lr] = ACC[n];                                   \
        }                                                             \
        __syncthreads();                                              \
        _Pragma("unroll")                                             \
        for (int q = 0; q < 4; ++q) {                                 \
            int idx = t + 256 * q;                                    \
            int r = idx >> 5, c = idx & 31;                           \
            float s = T[0][r][c] + T[1][r][c] + T[2][r][c] + T[3][r][c]; \
            STORE                                                     \
        }                                                             \
    }

    REDUCE_PASS(acc0, s2b[r * 64 + c] = s;)
    REDUCE_PASS(acc1, s2b[r * 64 + 32 + c] = s; s2b[(32 + c) * 64 + r] = s;)
    REDUCE_PASS(acc2, s2b[(32 + r) * 64 + 32 + c] = s;)
#undef REDUCE_PASS

    #pragma unroll
    for (int m = 16; m >= 1; m >>= 1) {
        #pragma unroll
        for (int j = 0; j < 8; ++j) s1a[j] += __shfl_xor(s1a[j], m);
    }
    if ((l & 31) == 0) {
        float* s1b = s1p + ((size_t)sp * BB + b) * P;
        int r0 = 2 * w + lh;
        #pragma unroll
        for (int j = 0; j < 8; ++j) s1b[r0 + 8 * j] = s1a[j];
    }
}

// ---------------- Kernel B: shrinkage + Newton-Schulz inverse sqrt ----------------
typedef float (*Mat68)[68];

__device__ inline void mm64f(Mat68 D, Mat68 A, Mat68 Bm, int t, float alpha, float beta)
{
    __syncthreads();
    const int r0 = (t >> 4) * 4, c0 = (t & 15) * 4;
    float acc[4][4];
    #pragma unroll
    for (int i = 0; i < 4; ++i)
        #pragma unroll
        for (int j = 0; j < 4; ++j) acc[i][j] = 0.f;
    #pragma unroll 4
    for (int k = 0; k < P; ++k) {
        float av[4], bv[4];
        *reinterpret_cast<float4*>(av) = *reinterpret_cast<const float4*>(&A[k][r0]);
        *reinterpret_cast<float4*>(bv) = *reinterpret_cast<const float4*>(&Bm[k][c0]);
        #pragma unroll
        for (int i = 0; i < 4; ++i)
            #pragma unroll
            for (int j = 0; j < 4; ++j) acc[i][j] += av[i] * bv[j];
    }
    __syncthreads();
    #pragma unroll
    for (int i = 0; i < 4; ++i)
        #pragma unroll
        for (int j = 0; j < 4; ++j)
            D[r0 + i][c0 + j] = alpha * acc[i][j] + ((r0 + i) == (c0 + j) ? beta : 0.f);
}

__global__ __launch_bounds__(256)
void whiten_kernel(const float* __restrict__ s2p, const float* __restrict__ s1p,
                   unsigned* __restrict__ sbb, float* __restrict__ tvec, int nsplit)
{
    __shared__ __align__(16) float B0[P][68], B1[P][68], B2[P][68], B3[P][68], B4[P][68];
    __shared__ float mus[P];
    __shared__ float red[2][4];
    const int b = blockIdx.x, t = threadIdx.x;

    if (t < P) {
        float s = 0.f;
        for (int sp = 0; sp < nsplit; ++sp) s += s1p[((size_t)sp * BB + b) * P + t];
        mus[t] = s * (1.0f / MM);
    }
    __syncthreads();

    float tr_part = 0.f, s2_part = 0.f;
    #pragma unroll
    for (int j = 0; j < 16; ++j) {
        int f = t + 256 * j;
        int i = f >> 6, jc = f & 63;
        float sum = 0.f;
        for (int sp = 0; sp < nsplit; ++sp)
            sum += s2p[((size_t)sp * BB + b) * (P * P) + f];
        float v = sum * (1.0f / MM) - mus[i] * mus[jc];
        B0[i][jc] = v;
        s2_part += v * v;
        if (i == jc) tr_part += v;
    }
    #pragma unroll
    for (int off = 32; off > 0; off >>= 1) {
        tr_part += __shfl_down(tr_part, off);
        s2_part += __shfl_down(s2_part, off);
    }
    if ((t & 63) == 0) { red[0][t >> 6] = tr_part; red[1][t >> 6] = s2_part; }
    __syncthreads();
    const float trace = red[0][0] + red[0][1] + red[0][2] + red[0][3];
    const float sum2  = red[1][0] + red[1][1] + red[1][2] + red[1][3];

    const float nf = (float)MM;
    const float num = (nf - 2.0f) / nf * sum2 + trace * trace;
    const float den = (nf + 2.0f) * (sum2 - trace * trace / (float)P);
    const float rho = (den > 0.f) ? fminf(num / den, 1.0f) : 1.0f;
    const float lam = trace * (1.0f / P);
    const float inv_s = 1.0f / lam;

    #pragma unroll
    for (int j = 0; j < 16; ++j) {
        int f = t + 256 * j;
        int i = f >> 6, jc = f & 63;
        float v = B0[i][jc];
        float sv = ((1.0f - rho) * v + ((i == jc) ? rho * lam : 0.f)) * inv_s;
        B0[i][jc] = sv;
        B2[i][jc] = ((i == jc) ? 1.5f : 0.f) - 0.5f * sv;
    }

    // Newton-Schulz, 3 maps (spectrum in [0.73,1.27] -> error ~6e-6)
    mm64f(B1, B0, B2, t, 1.f, 0.f);          // map1: Y1=A*T1, Z1=T1
    Mat68 Yc = B1, Zc = B2, Tc = B0, U = B3, V = B4;
    {
        mm64f(Tc, Zc, Yc, t, -0.5f, 1.5f);   // map2
        mm64f(U,  Yc, Tc, t, 1.f, 0.f);
        mm64f(V,  Tc, Zc, t, 1.f, 0.f);
        Mat68 tmp = Yc; Yc = U; U = tmp;
        tmp = Zc; Zc = V; V = tmp;
    }
    mm64f(Tc, Zc, Yc, t, -0.5f, 1.5f);       // map3
    mm64f(U,  Tc, Zc, t, 1.f, 0.f);          // U = A^{-1/2}
    __syncthreads();

    const float sc = rsqrtf(lam);
    // S_hat emitted as packed bf16 pairs along d: sbb[b][row][d/2] = {S[row][2d'], S[row][2d'+1]}
    unsigned* sb = sbb + (size_t)b * (P * P / 2);
    #pragma unroll
    for (int j = 0; j < 8; ++j) {
        int f2 = t + 256 * j;              // pair index
        int i = f2 >> 5, jc = (f2 & 31) * 2;
        sb[f2] = cvtpk(U[i][jc] * sc, U[i][jc + 1] * sc);
    }
    if (t < P) {
        float tv = 0.f;
        #pragma unroll
        for (int d = 0; d < P; ++d) tv += U[t][d] * mus[d];
        tvec[b * P + t] = tv * sc;
    }
}

// ---------------- Kernel C: Z = S_hat * x - (S_hat mu), MFMA ----------------
// A = S bf16 row-major (rows stride 72 bf16, 16B-aligned). B = X staged as
// (d,d+1)-pair dwords Xpk[dp][m] so B-frag (8 consecutive k at column m) is
// 4 conflict-free b32 reads (bank = 4*dp + m covers all 32 banks).
__global__ __launch_bounds__(256)
void apply_kernel(const float* __restrict__ x, const unsigned* __restrict__ sbb,
                  const float* __restrict__ tvec, float* __restrict__ out)
{
    __shared__ __align__(16) unsigned short Sb[P][72];   // 9216 B
    __shared__ __align__(16) unsigned Xpk[32][260];      // 33280 B
    __shared__ float tvs[P];
    const int mt = blockIdx.x, b = blockIdx.y;
    const int t = threadIdx.x;
    const int w = t >> 6, l = t & 63;
    const int lr = l & 31, lh = l >> 5;

    // stage S (2048 dwords) and tvec
    const unsigned* sb = sbb + (size_t)b * (P * P / 2);
    #pragma unroll
    for (int j = 0; j < 8; ++j) {
        int slot = t + 256 * j;
        int row = slot >> 5, cu = slot & 31;
        *reinterpret_cast<unsigned*>(&Sb[row][cu * 2]) = sb[slot];
    }
    if (t < P) tvs[t] = tvec[b * P + t];

    // stage X tile: rows 2dp,2dp+1 -> packed pair dwords
    const float* xb = x + (size_t)b * (P * MM) + mt * MT;
    #pragma unroll
    for (int j = 0; j < 8; ++j) {
        int slot = t + 256 * j;
        int dp = slot >> 6, m0 = (slot & 63) * 4;
        const float* xr = xb + (size_t)(2 * dp) * MM + m0;
        float4 a = *reinterpret_cast<const float4*>(xr);
        float4 c = *reinterpret_cast<const float4*>(xr + MM);
        unsigned u0 = cvtpk(a.x, c.x), u1 = cvtpk(a.y, c.y);
        unsigned u2 = cvtpk(a.z, c.z), u3 = cvtpk(a.w, c.w);
        uint4 pk = make_uint4(u0, u1, u2, u3);
        *reinterpret_cast<uint4*>(&Xpk[dp][m0]) = pk;
    }
    __syncthreads();

    f32x16 acc00 = {0,0,0,0,0,0,0,0,0,0,0,0,0,0,0,0};
    f32x16 acc01 = {0,0,0,0,0,0,0,0,0,0,0,0,0,0,0,0};
    f32x16 acc10 = {0,0,0,0,0,0,0,0,0,0,0,0,0,0,0,0};
    f32x16 acc11 = {0,0,0,0,0,0,0,0,0,0,0,0,0,0,0,0};

    const int cq0 = (2 * w) * 32 + lr, cq1 = (2 * w + 1) * 32 + lr;
    #pragma unroll
    for (int ks = 0; ks < 4; ++ks) {
        const char* arow = (const char*)&Sb[0][0] + ks * 32 + lh * 16;
        bf16x8 a0 = *(const bf16x8*)(arow + lr * 144);
        bf16x8 a1 = *(const bf16x8*)(arow + (32 + lr) * 144);
        const int dpb = ks * 8 + lh * 4;
        union { unsigned u[4]; bf16x8 v; } b0, b1;
        #pragma unroll
        for (int q = 0; q < 4; ++q) {
            b0.u[q] = Xpk[dpb + q][cq0];
            b1.u[q] = Xpk[dpb + q][cq1];
        }
        acc00 = MF(a0, b0.v, acc00);
        acc01 = MF(a0, b1.v, acc01);
        acc10 = MF(a1, b0.v, acc10);
        acc11 = MF(a1, b1.v, acc11);
    }

    float* ob = out + (size_t)b * (P * MM) + mt * MT;
#define STORE_TILE(ACC, RT, CQ)                                          \
    {                                                                    \
        _Pragma("unroll")                                                \
        for (int n = 0; n < 16; ++n) {                                   \
            int row = (RT) * 32 + (n & 3) + 8 * (n >> 2) + 4 * lh;       \
            ob[(size_t)row * MM + (CQ)] = ACC[n] - tvs[row];             \
        }                                                                \
    }
    STORE_TILE(acc00, 0, cq0)
    STORE_TILE(acc01, 0, cq1)
    STORE_TILE(acc10, 1, cq0)
    STORE_TILE(acc11, 1, cq1)
#undef STORE_TILE
}

extern "C" void kernel_launch(void* const* d_in, const int* in_sizes, int n_in,
                              void* d_out, int out_size, void* d_ws, size_t ws_size,
                              hipStream_t stream)
{
    const float* x = (const float*)d_in[0];
    float* out = (float*)d_out;

    // scratch (floats unless noted): s2p[ns][B][64][64] | s1p[ns][B][64] |
    // sbb[B][64][32] (uint bf16-pairs) | tvec[B][64]
    auto need = [](int ns) -> size_t {
        return ((size_t)ns * BB * P * P + (size_t)ns * BB * P
                + (size_t)BB * P * P / 2 + (size_t)BB * P) * sizeof(float);
    };
    int nsplit = 4;
    if (ws_size < need(4)) nsplit = 2;
    if (ws_size < need(2)) nsplit = 1;

    float* s2p  = (float*)d_ws;
    float* s1p  = s2p + (size_t)nsplit * BB * P * P;
    unsigned* sbb = (unsigned*)(s1p + (size_t)nsplit * BB * P);
    float* tvec = (float*)(sbb + (size_t)BB * P * P / 2);

    covpart_kernel<<<dim3(BB, nsplit), 256, 0, stream>>>(x, s2p, s1p, nsplit);
    whiten_kernel<<<dim3(BB), 256, 0, stream>>>(s2p, s1p, sbb, tvec, nsplit);
    apply_kernel<<<dim3(MM / MT, BB), 256, 0, stream>>>(x, sbb, tvec, out);
}